// Round 11
// baseline (32.594 us; speedup 1.0000x reference)
//
#include <hip/hip_runtime.h>
#include <math.h>

#define N_PTS 4096
#define FB (N_PTS * 3)            // floats per batch = 12288
#define BLK 256
#define STAGES 4                  // 4 points/thread/stage * 4 stages = 16 pts/thread
#define STATS 17

// Fixed-point pack: low 54 bits = sum of rmsd*2^36 (rmsd<64 guaranteed by
// problem scale ~24; 1024*24*2^36 < 2^52), bits 54+ = arrival count.
#define FX_SHIFT 36
#define CNT_SHIFT 54
#define FX_MASK ((1ULL << CNT_SHIFT) - 1ULL)

struct __align__(4) f3 { float x, y, z; };

// One block per batch, register-only streaming (r10's proven body): each
// thread owns 16 whole points via global_load_dwordx3 (12B/lane, lane-stride
// 12B -> 768B contiguous per instr; coalesced AND point-aligned, no LDS).
// 2-deep pipeline: stage s+1's 8 loads fly during stage s's 92 FMAs.
// Tail: single packed u64 atomicAdd accumulates the fixed-point RMSD sum AND
// elects the last block (old>>54 == nblocks-1), which writes the mean.
// Deterministic (integer adds commute); NO __threadfence (r5/r6: per-block
// device fences = whole-XCD L2 writebacks, 420 us); visibility flows through
// the atomic RMW's returned old value.
__global__ __launch_bounds__(BLK) void kabsch_batch(const f3* __restrict__ pred,
                                                    const f3* __restrict__ tru,
                                                    unsigned long long* __restrict__ pk,
                                                    float* __restrict__ out,
                                                    int nblocks) {
    const int b = blockIdx.x, tid = threadIdx.x;
    const f3* Pb = pred + (size_t)b * N_PTS;
    const f3* Tb = tru  + (size_t)b * N_PTS;

    float a[STATS];
    #pragma unroll
    for (int i = 0; i < STATS; ++i) a[i] = 0.0f;

#define ACC(p, t) do {                                                          \
        a[0] += (p).x; a[1] += (p).y; a[2] += (p).z;                            \
        a[3] += (t).x; a[4] += (t).y; a[5] += (t).z;                            \
        a[6] = fmaf((p).x,(p).x, fmaf((p).y,(p).y, fmaf((p).z,(p).z, a[6])));   \
        a[7] = fmaf((t).x,(t).x, fmaf((t).y,(t).y, fmaf((t).z,(t).z, a[7])));   \
        a[8]  = fmaf((p).x,(t).x, a[8]);  a[9]  = fmaf((p).x,(t).y, a[9]);      \
        a[10] = fmaf((p).x,(t).z, a[10]); a[11] = fmaf((p).y,(t).x, a[11]);     \
        a[12] = fmaf((p).y,(t).y, a[12]); a[13] = fmaf((p).y,(t).z, a[13]);     \
        a[14] = fmaf((p).z,(t).x, a[14]); a[15] = fmaf((p).z,(t).y, a[15]);     \
        a[16] = fmaf((p).z,(t).z, a[16]);                                       \
    } while (0)

    // Stage 0 preload (8 dwordx3 in flight).
    f3 pc0 = Pb[0 * BLK + tid], pc1 = Pb[1 * BLK + tid],
       pc2 = Pb[2 * BLK + tid], pc3 = Pb[3 * BLK + tid];
    f3 tc0 = Tb[0 * BLK + tid], tc1 = Tb[1 * BLK + tid],
       tc2 = Tb[2 * BLK + tid], tc3 = Tb[3 * BLK + tid];

    #pragma unroll
    for (int s = 0; s < STAGES; ++s) {
        f3 pn0, pn1, pn2, pn3, tn0, tn1, tn2, tn3;
        if (s < STAGES - 1) {
            const int off = (s + 1) * (STAGES * BLK);   // +1024 points
            pn0 = Pb[off + 0 * BLK + tid]; pn1 = Pb[off + 1 * BLK + tid];
            pn2 = Pb[off + 2 * BLK + tid]; pn3 = Pb[off + 3 * BLK + tid];
            tn0 = Tb[off + 0 * BLK + tid]; tn1 = Tb[off + 1 * BLK + tid];
            tn2 = Tb[off + 2 * BLK + tid]; tn3 = Tb[off + 3 * BLK + tid];
        }
        ACC(pc0, tc0); ACC(pc1, tc1); ACC(pc2, tc2); ACC(pc3, tc3);
        if (s < STAGES - 1) {
            pc0 = pn0; pc1 = pn1; pc2 = pn2; pc3 = pn3;
            tc0 = tn0; tc1 = tn1; tc2 = tn2; tc3 = tn3;
        }
    }
#undef ACC

    // Block reduction: 2-stage butterfly -> 4-lane-group sums, LDS transpose,
    // threads 0..16 row-sum, stats -> LDS, thread 0 eigensolve.
    #pragma unroll
    for (int i = 0; i < STATS; ++i) {
        a[i] += __shfl_xor(a[i], 1, 64);
        a[i] += __shfl_xor(a[i], 2, 64);
    }
    __shared__ float tl[STATS * 68 + 32];          // [STATS][68] stride 272B + scratch
    const int grp = tid >> 2, sub = tid & 3;
    #pragma unroll
    for (int k = 0; k < 5; ++k) {
        const int s = sub + 4 * k;
        if (s < STATS) tl[s * 68 + grp] = a[s];
    }
    __syncthreads();
    float* fin = tl + STATS * 68;
    if (tid < STATS) {
        const float4* row = reinterpret_cast<const float4*>(&tl[tid * 68]);
        float4 acc4 = row[0];
        #pragma unroll
        for (int k = 1; k < BLK / 16; ++k) {
            float4 v = row[k];
            acc4.x += v.x; acc4.y += v.y; acc4.z += v.z; acc4.w += v.w;
        }
        fin[tid] = (acc4.x + acc4.y) + (acc4.z + acc4.w);
    }
    __syncthreads();
    if (tid == 0) {
        float w[STATS];
        #pragma unroll
        for (int i = 0; i < STATS; ++i) w[i] = fin[i];

        const float invN = 1.0f / (float)N_PTS;
        float sp[3] = {w[0], w[1], w[2]};
        float st[3] = {w[3], w[4], w[5]};
        float A[3][3];
        #pragma unroll
        for (int i = 0; i < 3; ++i)
            #pragma unroll
            for (int j = 0; j < 3; ++j)
                A[i][j] = w[8 + i * 3 + j] - sp[i] * st[j] * invN;
        float Sp = w[6] - (sp[0] * sp[0] + sp[1] * sp[1] + sp[2] * sp[2]) * invN;
        float St = w[7] - (st[0] * st[0] + st[1] * st[1] + st[2] * st[2]) * invN;

        float detA = A[0][0] * (A[1][1] * A[2][2] - A[1][2] * A[2][1])
                   - A[0][1] * (A[1][0] * A[2][2] - A[1][2] * A[2][0])
                   + A[0][2] * (A[1][0] * A[2][1] - A[1][1] * A[2][0]);

        // G = A^T A (symmetric, PSD)
        float G00 = A[0][0]*A[0][0] + A[1][0]*A[1][0] + A[2][0]*A[2][0];
        float G11 = A[0][1]*A[0][1] + A[1][1]*A[1][1] + A[2][1]*A[2][1];
        float G22 = A[0][2]*A[0][2] + A[1][2]*A[1][2] + A[2][2]*A[2][2];
        float G01 = A[0][0]*A[0][1] + A[1][0]*A[1][1] + A[2][0]*A[2][1];
        float G02 = A[0][0]*A[0][2] + A[1][0]*A[1][2] + A[2][0]*A[2][2];
        float G12 = A[0][1]*A[0][2] + A[1][1]*A[1][2] + A[2][1]*A[2][2];

        // Closed-form symmetric 3x3 eigenvalues (descending e1 >= e2 >= e3).
        float q = (G00 + G11 + G22) * (1.0f / 3.0f);
        float p1 = G01 * G01 + G02 * G02 + G12 * G12;
        float b00 = G00 - q, b11 = G11 - q, b22 = G22 - q;
        float p2 = b00 * b00 + b11 * b11 + b22 * b22 + 2.0f * p1;
        float p = sqrtf(p2 * (1.0f / 6.0f));
        float e1, e2, e3;
        if (p > 1e-30f + 1e-6f * fabsf(q)) {
            float ip = 1.0f / p;
            float C00 = b00 * ip, C11 = b11 * ip, C22 = b22 * ip;
            float C01 = G01 * ip, C02 = G02 * ip, C12 = G12 * ip;
            float r = 0.5f * (C00 * (C11 * C22 - C12 * C12)
                            - C01 * (C01 * C22 - C12 * C02)
                            + C02 * (C01 * C12 - C11 * C02));
            r = fminf(1.0f, fmaxf(-1.0f, r));
            float phi = acosf(r) * (1.0f / 3.0f);
            e1 = q + 2.0f * p * __cosf(phi);
            e3 = q + 2.0f * p * __cosf(phi + 2.0943951023931953f);  // + 2*pi/3
            e2 = 3.0f * q - e1 - e3;
        } else {
            e1 = e2 = e3 = q;
        }
        float s1 = sqrtf(fmaxf(e1, 0.0f));
        float s2 = sqrtf(fmaxf(e2, 0.0f));
        float s3 = sqrtf(fmaxf(e3, 0.0f));  // smallest singular value
        float d = (detA < 0.0f) ? -1.0f : 1.0f;
        float tr = s1 + s2 + d * s3;
        float msd = (Sp + St - 2.0f * tr) * invN;
        float rmsd = sqrtf(fmaxf(msd, 0.0f));

        // Packed accumulate + last-block election. Integer adds are exact and
        // commutative -> deterministic regardless of arrival order.
        unsigned long long fx =
            (unsigned long long)(long long)llrintf(rmsd * (float)(1ULL << FX_SHIFT));
        unsigned long long inc = (1ULL << CNT_SHIFT) | (fx & FX_MASK);
        unsigned long long old = atomicAdd(pk, inc);
        if ((old >> CNT_SHIFT) == (unsigned long long)(nblocks - 1)) {
            unsigned long long total = (old & FX_MASK) + (fx & FX_MASK);
            out[0] = (float)((double)total
                             * (1.0 / (double)(1ULL << FX_SHIFT))
                             / (double)nblocks);
        }
    }
}

extern "C" void kernel_launch(void* const* d_in, const int* in_sizes, int n_in,
                              void* d_out, int out_size, void* d_ws, size_t ws_size,
                              hipStream_t stream) {
    const f3* pred = (const f3*)d_in[0];
    const f3* tru  = (const f3*)d_in[1];
    float* out = (float*)d_out;
    unsigned long long* pk = (unsigned long long*)d_ws;
    const int B = in_sizes[0] / FB;     // 1024

    hipMemsetAsync(pk, 0, sizeof(unsigned long long), stream);   // reset pack each call
    kabsch_batch<<<dim3(B), dim3(BLK), 0, stream>>>(pred, tru, pk, out, B);
}

// Round 12
// 23.613 us; speedup vs baseline: 1.3804x; 1.3804x over previous
//
#include <hip/hip_runtime.h>
#include <math.h>

#define N_PTS 4096
#define FB (N_PTS * 3)            // floats per batch = 12288
#define BLK 256
#define STAGES 4                  // 4 points/thread/stage * 4 stages = 16 pts/thread
#define STATS 17

struct __align__(4) f3 { float x, y, z; };

__device__ inline float wave_reduce_sum_f32(float v) {
    #pragma unroll
    for (int off = 32; off > 0; off >>= 1) v += __shfl_xor(v, off, 64);
    return v;
}

// One block per batch, register-only streaming: each thread owns 16 whole
// points loaded as global_load_dwordx3 (12B/lane, lane-stride 12B -> 768B
// contiguous per instruction: coalesced AND point-aligned, so no LDS staging).
// 2-deep pipeline: stage s+1's 8 loads are in flight while stage s's 92 FMAs
// run. DO NOT touch the tail code: r11 added a packed-u64 atomic finish and
// the compiler's occupancy heuristic flipped to 8 waves/EU (VGPR 56), which
// serialized the load pipeline (41 us warm AND cold). This exact two-kernel
// form is the proven-fast codegen (23.8 us).
__global__ __launch_bounds__(BLK) void kabsch_batch(const f3* __restrict__ pred,
                                                    const f3* __restrict__ tru,
                                                    float* __restrict__ rmsds) {
    const int b = blockIdx.x, tid = threadIdx.x;
    const f3* Pb = pred + (size_t)b * N_PTS;
    const f3* Tb = tru  + (size_t)b * N_PTS;

    float a[STATS];
    #pragma unroll
    for (int i = 0; i < STATS; ++i) a[i] = 0.0f;

#define ACC(p, t) do {                                                          \
        a[0] += (p).x; a[1] += (p).y; a[2] += (p).z;                            \
        a[3] += (t).x; a[4] += (t).y; a[5] += (t).z;                            \
        a[6] = fmaf((p).x,(p).x, fmaf((p).y,(p).y, fmaf((p).z,(p).z, a[6])));   \
        a[7] = fmaf((t).x,(t).x, fmaf((t).y,(t).y, fmaf((t).z,(t).z, a[7])));   \
        a[8]  = fmaf((p).x,(t).x, a[8]);  a[9]  = fmaf((p).x,(t).y, a[9]);      \
        a[10] = fmaf((p).x,(t).z, a[10]); a[11] = fmaf((p).y,(t).x, a[11]);     \
        a[12] = fmaf((p).y,(t).y, a[12]); a[13] = fmaf((p).y,(t).z, a[13]);     \
        a[14] = fmaf((p).z,(t).x, a[14]); a[15] = fmaf((p).z,(t).y, a[15]);     \
        a[16] = fmaf((p).z,(t).z, a[16]);                                       \
    } while (0)

    // Stage 0 preload (8 dwordx3 in flight).
    f3 pc0 = Pb[0 * BLK + tid], pc1 = Pb[1 * BLK + tid],
       pc2 = Pb[2 * BLK + tid], pc3 = Pb[3 * BLK + tid];
    f3 tc0 = Tb[0 * BLK + tid], tc1 = Tb[1 * BLK + tid],
       tc2 = Tb[2 * BLK + tid], tc3 = Tb[3 * BLK + tid];

    #pragma unroll
    for (int s = 0; s < STAGES; ++s) {
        f3 pn0, pn1, pn2, pn3, tn0, tn1, tn2, tn3;
        if (s < STAGES - 1) {
            const int off = (s + 1) * (STAGES * BLK);   // +1024 points
            pn0 = Pb[off + 0 * BLK + tid]; pn1 = Pb[off + 1 * BLK + tid];
            pn2 = Pb[off + 2 * BLK + tid]; pn3 = Pb[off + 3 * BLK + tid];
            tn0 = Tb[off + 0 * BLK + tid]; tn1 = Tb[off + 1 * BLK + tid];
            tn2 = Tb[off + 2 * BLK + tid]; tn3 = Tb[off + 3 * BLK + tid];
        }
        ACC(pc0, tc0); ACC(pc1, tc1); ACC(pc2, tc2); ACC(pc3, tc3);
        if (s < STAGES - 1) {
            pc0 = pn0; pc1 = pn1; pc2 = pn2; pc3 = pn3;
            tc0 = tn0; tc1 = tn1; tc2 = tn2; tc3 = tn3;
        }
    }
#undef ACC

    // Block reduction: 2-stage butterfly -> 4-lane-group sums, LDS transpose,
    // threads 0..16 row-sum, stats -> LDS, thread 0 eigensolve.
    #pragma unroll
    for (int i = 0; i < STATS; ++i) {
        a[i] += __shfl_xor(a[i], 1, 64);
        a[i] += __shfl_xor(a[i], 2, 64);
    }
    __shared__ float tl[STATS * 68 + 32];          // [STATS][68] stride 272B + scratch
    const int grp = tid >> 2, sub = tid & 3;
    #pragma unroll
    for (int k = 0; k < 5; ++k) {
        const int s = sub + 4 * k;
        if (s < STATS) tl[s * 68 + grp] = a[s];
    }
    __syncthreads();
    float* fin = tl + STATS * 68;
    if (tid < STATS) {
        const float4* row = reinterpret_cast<const float4*>(&tl[tid * 68]);
        float4 acc4 = row[0];
        #pragma unroll
        for (int k = 1; k < BLK / 16; ++k) {
            float4 v = row[k];
            acc4.x += v.x; acc4.y += v.y; acc4.z += v.z; acc4.w += v.w;
        }
        fin[tid] = (acc4.x + acc4.y) + (acc4.z + acc4.w);
    }
    __syncthreads();
    if (tid == 0) {
        float w[STATS];
        #pragma unroll
        for (int i = 0; i < STATS; ++i) w[i] = fin[i];

        const float invN = 1.0f / (float)N_PTS;
        float sp[3] = {w[0], w[1], w[2]};
        float st[3] = {w[3], w[4], w[5]};
        float A[3][3];
        #pragma unroll
        for (int i = 0; i < 3; ++i)
            #pragma unroll
            for (int j = 0; j < 3; ++j)
                A[i][j] = w[8 + i * 3 + j] - sp[i] * st[j] * invN;
        float Sp = w[6] - (sp[0] * sp[0] + sp[1] * sp[1] + sp[2] * sp[2]) * invN;
        float St = w[7] - (st[0] * st[0] + st[1] * st[1] + st[2] * st[2]) * invN;

        float detA = A[0][0] * (A[1][1] * A[2][2] - A[1][2] * A[2][1])
                   - A[0][1] * (A[1][0] * A[2][2] - A[1][2] * A[2][0])
                   + A[0][2] * (A[1][0] * A[2][1] - A[1][1] * A[2][0]);

        // G = A^T A (symmetric, PSD)
        float G00 = A[0][0]*A[0][0] + A[1][0]*A[1][0] + A[2][0]*A[2][0];
        float G11 = A[0][1]*A[0][1] + A[1][1]*A[1][1] + A[2][1]*A[2][1];
        float G22 = A[0][2]*A[0][2] + A[1][2]*A[1][2] + A[2][2]*A[2][2];
        float G01 = A[0][0]*A[0][1] + A[1][0]*A[1][1] + A[2][0]*A[2][1];
        float G02 = A[0][0]*A[0][2] + A[1][0]*A[1][2] + A[2][0]*A[2][2];
        float G12 = A[0][1]*A[0][2] + A[1][1]*A[1][2] + A[2][1]*A[2][2];

        // Closed-form symmetric 3x3 eigenvalues (descending e1 >= e2 >= e3).
        float q = (G00 + G11 + G22) * (1.0f / 3.0f);
        float p1 = G01 * G01 + G02 * G02 + G12 * G12;
        float b00 = G00 - q, b11 = G11 - q, b22 = G22 - q;
        float p2 = b00 * b00 + b11 * b11 + b22 * b22 + 2.0f * p1;
        float p = sqrtf(p2 * (1.0f / 6.0f));
        float e1, e2, e3;
        if (p > 1e-30f + 1e-6f * fabsf(q)) {
            float ip = 1.0f / p;
            float C00 = b00 * ip, C11 = b11 * ip, C22 = b22 * ip;
            float C01 = G01 * ip, C02 = G02 * ip, C12 = G12 * ip;
            float r = 0.5f * (C00 * (C11 * C22 - C12 * C12)
                            - C01 * (C01 * C22 - C12 * C02)
                            + C02 * (C01 * C12 - C11 * C02));
            r = fminf(1.0f, fmaxf(-1.0f, r));
            float phi = acosf(r) * (1.0f / 3.0f);
            e1 = q + 2.0f * p * __cosf(phi);
            e3 = q + 2.0f * p * __cosf(phi + 2.0943951023931953f);  // + 2*pi/3
            e2 = 3.0f * q - e1 - e3;
        } else {
            e1 = e2 = e3 = q;
        }
        float s1 = sqrtf(fmaxf(e1, 0.0f));
        float s2 = sqrtf(fmaxf(e2, 0.0f));
        float s3 = sqrtf(fmaxf(e3, 0.0f));  // smallest singular value
        float d = (detA < 0.0f) ? -1.0f : 1.0f;
        float tr = s1 + s2 + d * s3;
        float msd = (Sp + St - 2.0f * tr) * invN;
        rmsds[b] = sqrtf(fmaxf(msd, 0.0f));
    }
}

// Tiny mean over B per-batch RMSDs: 1 block, 256 threads, one float4 each.
__global__ __launch_bounds__(BLK) void kabsch_mean(const float* __restrict__ rmsds,
                                                   float* __restrict__ out, int B) {
    const int tid = threadIdx.x;
    const float4* r4 = reinterpret_cast<const float4*>(rmsds);
    float4 v = r4[tid];                 // B = 1024 -> 256 float4s
    float s = (v.x + v.y) + (v.z + v.w);
    s = wave_reduce_sum_f32(s);
    __shared__ float red[4];
    if ((tid & 63) == 0) red[tid >> 6] = s;
    __syncthreads();
    if (tid == 0) out[0] = ((red[0] + red[1]) + (red[2] + red[3])) / (float)B;
}

extern "C" void kernel_launch(void* const* d_in, const int* in_sizes, int n_in,
                              void* d_out, int out_size, void* d_ws, size_t ws_size,
                              hipStream_t stream) {
    const f3* pred = (const f3*)d_in[0];
    const f3* tru  = (const f3*)d_in[1];
    float* out = (float*)d_out;
    float* rmsds = (float*)d_ws;
    const int B = in_sizes[0] / FB;     // 1024

    kabsch_batch<<<dim3(B), dim3(BLK), 0, stream>>>(pred, tru, rmsds);
    kabsch_mean<<<dim3(1), dim3(BLK), 0, stream>>>(rmsds, out, B);
}